// Round 8
// baseline (219.151 us; speedup 1.0000x reference)
//
#include <hip/hip_runtime.h>
#include <cmath>

#define Bn 64
#define Sn 512
#define Hn 768
#define Cn 50
#define Mn 2000
#define Tn (Bn*Sn)   // 32768
#define MCAP 1024    // max active tokens per mention/utt row (E=328/655, +many sigma)
#define NP 128       // t-partitions for k_out
#define TC 256       // tokens per partition
#define HT 128       // h columns per tile

// ---------------- K1: per-token projections, weights in registers ----------------
__global__ __launch_bounds__(256) void k_proj(
    const float* __restrict__ se,
    const float* __restrict__ w_ntok, const float* __restrict__ b_ntok,
    const float* __restrict__ w_name,
    const float* __restrict__ w_mtok, const float* __restrict__ b_mtok,
    const float* __restrict__ w_men,
    const float* __restrict__ w_utt, const float* __restrict__ b_utt,
    const float* __restrict__ w_comb,
    float* __restrict__ nts, float* __restrict__ p_name,
    float* __restrict__ mts, float* __restrict__ p_men,
    float* __restrict__ uts, float* __restrict__ p_comb)
{
    int wv = threadIdx.x >> 6, lane = threadIdx.x & 63;
    int gw = blockIdx.x * 4 + wv;            // 0..4095, 8 rows each
    float4 w[6][3];
    const float4* warr[6] = {(const float4*)w_ntok, (const float4*)w_name,
                             (const float4*)w_mtok, (const float4*)w_men,
                             (const float4*)w_utt,  (const float4*)w_comb};
#pragma unroll
    for (int j = 0; j < 6; j++)
#pragma unroll
        for (int k = 0; k < 3; k++) w[j][k] = warr[j][lane + 64*k];
    float b0 = b_ntok[0], b2 = b_mtok[0], b4 = b_utt[0];
    for (int rr = 0; rr < 8; rr++) {
        int r = gw*8 + rr;
        const float4* se4 = (const float4*)(se + (size_t)r * Hn);
        float s0=0,s1=0,s2=0,s3=0,s4=0,s5=0;
#pragma unroll
        for (int k = 0; k < 3; k++) {
            float4 v = se4[lane + 64*k];
            s0 += v.x*w[0][k].x + v.y*w[0][k].y + v.z*w[0][k].z + v.w*w[0][k].w;
            s1 += v.x*w[1][k].x + v.y*w[1][k].y + v.z*w[1][k].z + v.w*w[1][k].w;
            s2 += v.x*w[2][k].x + v.y*w[2][k].y + v.z*w[2][k].z + v.w*w[2][k].w;
            s3 += v.x*w[3][k].x + v.y*w[3][k].y + v.z*w[3][k].z + v.w*w[3][k].w;
            s4 += v.x*w[4][k].x + v.y*w[4][k].y + v.z*w[4][k].z + v.w*w[4][k].w;
            s5 += v.x*w[5][k].x + v.y*w[5][k].y + v.z*w[5][k].z + v.w*w[5][k].w;
        }
#pragma unroll
        for (int off = 32; off >= 1; off >>= 1) {
            s0 += __shfl_xor(s0, off); s1 += __shfl_xor(s1, off);
            s2 += __shfl_xor(s2, off); s3 += __shfl_xor(s3, off);
            s4 += __shfl_xor(s4, off); s5 += __shfl_xor(s5, off);
        }
        if (lane == 0) {
            nts[r]    = s0 + b0;
            p_name[r] = s1;
            mts[r]    = s2 + b2;
            p_men[r]  = s3;
            uts[r]    = s4 + b4;
            p_comb[r] = s5;
        }
    }
}

// ---------------- K2: merged scan — mentions (0..1999) + utt (2000..2049) + names (2050..2849) ----
__global__ __launch_bounds__(256) void k_scan(
    const float* __restrict__ mmask, const float* __restrict__ mts,
    const float* __restrict__ p_men, const float* __restrict__ p_comb,
    const float* __restrict__ b_men_p,
    const float* __restrict__ umask, const float* __restrict__ uts,
    const float* __restrict__ nm_mask, const float* __restrict__ nts,
    const float* __restrict__ p_name, const float* __restrict__ b_name_p,
    float* __restrict__ m_score, float* __restrict__ mcv, float* __restrict__ denm,
    int* __restrict__ midx, float* __restrict__ mwgt, int* __restrict__ mcnt,
    float* __restrict__ m1u, float* __restrict__ denu, float* __restrict__ sc2,
    float* __restrict__ n_score, float* __restrict__ sc_n,
    float* __restrict__ m1n, float* __restrict__ denn)
{
    int tid = threadIdx.x;
    int wv = tid >> 6, lane = tid & 63;

    __shared__ int scnt;
    __shared__ int   sT[MCAP];
    __shared__ float sV[MCAP];
    __shared__ float sr1[4], sr2[4], sr3[4], sr4[4];

    if (blockIdx.x >= Mn + Cn) {
        // ---- names: one wave per (c,b) ----
        int idx = (blockIdx.x - Mn - Cn) * 4 + wv;   // c*Bn + b
        int c = idx >> 6, b = idx & 63;
        float v[8];
        float mx = -INFINITY;
#pragma unroll
        for (int k = 0; k < 8; k++) {
            int s = lane + 64*k;
            float val = nm_mask[c*Sn + s] + nts[b*Sn + s];   // -inf if masked
            v[k] = val;
            mx = fmaxf(mx, val);
        }
#pragma unroll
        for (int off = 32; off >= 1; off >>= 1) mx = fmaxf(mx, __shfl_xor(mx, off));
        float d = 0, sn = 0, sc = 0;
#pragma unroll
        for (int k = 0; k < 8; k++) {
            int s = lane + 64*k;
            int t = b*Sn + s;
            float e = __expf(v[k] - mx);
            d += e; sn += e * p_name[t]; sc += e * p_comb[t];
        }
#pragma unroll
        for (int off = 32; off >= 1; off >>= 1) {
            d += __shfl_xor(d, off); sn += __shfl_xor(sn, off); sc += __shfl_xor(sc, off);
        }
        if (lane == 0) {
            n_score[idx] = sn / d + b_name_p[0];
            sc_n[idx]    = sc / d;
            m1n[idx]     = mx;
            denn[idx]    = d;
        }
        return;
    }

    bool isU = blockIdx.x >= Mn;
    int row = isU ? (blockIdx.x - Mn) : blockIdx.x;
    if (tid == 0) scnt = 0;
    __syncthreads();

    const float4* row4 = (const float4*)((isU ? umask : mmask) + (size_t)row * Tn);
    const float*  vals = isU ? uts : mts;

    // phase 1: ballot compaction of indices only (mask stream is the sole load)
    for (int k = 0; k < Tn/4/256; k++) {
        int i = tid + k*256;
        float4 f = row4[i];
        float fm[4] = {f.x, f.y, f.z, f.w};
#pragma unroll
        for (int j = 0; j < 4; j++) {
            bool act = (fm[j] == 0.0f);
            unsigned long long bm = __ballot(act);
            if (bm) {
                int tot = __popcll(bm);
                int pos = __popcll(bm & ((1ull << lane) - 1ull));
                int base = 0;
                if (lane == 0) base = atomicAdd(&scnt, tot);
                base = __builtin_amdgcn_readfirstlane(base);
                int s = base + pos;
                if (act && s < MCAP) sT[s] = i*4 + j;
            }
        }
    }
    __syncthreads();
    int n = (scnt < MCAP) ? scnt : MCAP;

    // phase 2: gather values (L2-resident) + dense max
    float mx = -INFINITY;
    for (int i = tid; i < n; i += 256) {
        float v = vals[sT[i]];
        sV[i] = v;
        mx = fmaxf(mx, v);
    }
#pragma unroll
    for (int off = 32; off >= 1; off >>= 1) mx = fmaxf(mx, __shfl_xor(mx, off));
    if (lane == 0) sr1[wv] = mx;
    __syncthreads();
    mx = fmaxf(fmaxf(sr1[0], sr1[1]), fmaxf(sr1[2], sr1[3]));

    // phase 3: exp-sum + projection gathers (+ weight list for mentions)
    float d = 0, nm = 0, nc = 0;
    if (!isU) {
        int* gi = midx + (size_t)row * MCAP;
        float* gwp = mwgt + (size_t)row * MCAP;
        for (int i = tid; i < n; i += 256) {
            float e = __expf(sV[i] - mx);
            int t = sT[i];
            d += e; nm += e * p_men[t]; nc += e * p_comb[t];
            gi[i] = t; gwp[i] = e;
        }
    } else {
        for (int i = tid; i < n; i += 256) {
            float e = __expf(sV[i] - mx);
            d += e; nc += e * p_comb[sT[i]];
        }
    }
#pragma unroll
    for (int off = 32; off >= 1; off >>= 1) {
        d += __shfl_xor(d, off); nm += __shfl_xor(nm, off); nc += __shfl_xor(nc, off);
    }
    if (lane == 0) { sr2[wv] = d; sr3[wv] = nm; sr4[wv] = nc; }
    __syncthreads();
    if (tid == 0) {
        float dd = sr2[0]+sr2[1]+sr2[2]+sr2[3];
        float sm = sr3[0]+sr3[1]+sr3[2]+sr3[3];
        float sc = sr4[0]+sr4[1]+sr4[2]+sr4[3];
        if (!isU) {
            m_score[row] = sm/dd + b_men_p[0];
            mcv[row]     = sc/dd;
            denm[row]    = dd;
            mcnt[row]    = n;
        } else {
            m1u[row]  = mx;
            denu[row] = dd;
            sc2[row]  = (dd > 0.f) ? sc/dd : 0.f;
        }
    }
}

// ---------------- K3: small reductions — names-b softmax (0..49) + segment softmax (50..99) ----
__global__ __launch_bounds__(256) void k_small(
    const float* __restrict__ n_score, const float* __restrict__ sc_n,
    const int* __restrict__ seg, const float* __restrict__ m_score, const float* __restrict__ mcv,
    float* __restrict__ bw, float* __restrict__ sc0,
    float* __restrict__ segmax, float* __restrict__ segden, float* __restrict__ sc1)
{
    int tid = threadIdx.x;
    if (blockIdx.x < Cn) {
        int c = blockIdx.x;
        if (tid < 64) {
            int lane = tid;
            int idx = c*Bn + lane;
            float v = n_score[idx];
            float mx = v;
#pragma unroll
            for (int off = 32; off >= 1; off >>= 1) mx = fmaxf(mx, __shfl_xor(mx, off));
            float e = __expf(v - mx);
            float d = e, s = e * sc_n[idx];
#pragma unroll
            for (int off = 32; off >= 1; off >>= 1) { d += __shfl_xor(d, off); s += __shfl_xor(s, off); }
            bw[idx] = e / d;
            if (lane == 0) sc0[c] = s / d;
        }
    } else {
        int c = blockIdx.x - Cn;
        float mx = -INFINITY;
        for (int m = tid; m < Mn; m += 256)
            if (seg[m] == c) mx = fmaxf(mx, m_score[m]);
        __shared__ float sm[256];
        sm[tid] = mx; __syncthreads();
        for (int s = 128; s > 0; s >>= 1) { if (tid < s) sm[tid] = fmaxf(sm[tid], sm[tid+s]); __syncthreads(); }
        mx = sm[0];
        float d = 0, s1 = 0;
        if (mx != -INFINITY) {
            for (int m = tid; m < Mn; m += 256)
                if (seg[m] == c) { float e = __expf(m_score[m] - mx); d += e; s1 += e * mcv[m]; }
        }
        __shared__ float sd[256], ss[256];
        sd[tid] = d; ss[tid] = s1; __syncthreads();
        for (int s = 128; s > 0; s >>= 1) { if (tid < s) { sd[tid] += sd[tid+s]; ss[tid] += ss[tid+s]; } __syncthreads(); }
        if (tid == 0) {
            segmax[c] = mx;
            segden[c] = sd[0];
            sc1[c]    = (sd[0] > 0.f) ? ss[0]/sd[0] : 0.f;
        }
    }
}

// ---------------- combine-inline helper ----------------
__device__ inline void combine_attn(float sc0v, float sc1v, float sc2v,
                                    float sdn, float dnu, float bc,
                                    float& a0, float& a1, float& a2)
{
    float s0 = sc0v + bc;
    bool hasm = sdn > 0.f, hasu = dnu > 0.f;
    float s1 = hasm ? sc1v + bc : -INFINITY;
    float s2 = hasu ? sc2v + bc : -INFINITY;
    float mx = fmaxf(s0, fmaxf(s1, s2));
    float e0 = __expf(s0 - mx);
    float e1 = hasm ? __expf(s1 - mx) : 0.f;
    float e2 = hasu ? __expf(s2 - mx) : 0.f;
    float dd = e0 + e1 + e2;
    a0 = e0/dd; a1 = e1/dd; a2 = e2/dd;
}

// ---------------- K4: dense W init = name + utterance (no atomics) ----------------
__global__ __launch_bounds__(256) void k_buildW(
    const float* __restrict__ nm_mask, const float* __restrict__ nts,
    const float* __restrict__ m1n, const float* __restrict__ denn,
    const float* __restrict__ bw,
    const float* __restrict__ umask, const float* __restrict__ uts,
    const float* __restrict__ m1u, const float* __restrict__ denu,
    const float* __restrict__ sc0, const float* __restrict__ sc1, const float* __restrict__ sc2,
    const float* __restrict__ segden, const float* __restrict__ b_comb_p,
    float* __restrict__ W)
{
    int c = blockIdx.y;
    float a0, a1, a2;
    combine_attn(sc0[c], sc1[c], sc2[c], segden[c], denu[c], b_comb_p[0], a0, a1, a2);
    int t0 = (blockIdx.x * 256 + threadIdx.x) * 4;
    int b = t0 >> 9;
    float4 um = *(const float4*)(umask + (size_t)c * Tn + t0);
    float cn = a0 * bw[c*Bn + b] / denn[c*Bn + b];
    float m1nc = m1n[c*Bn + b];
    float du = denu[c];
    float cu = (du > 0.f) ? a2 / du : 0.f;
    float m1uc = m1u[c];
    float umj[4] = {um.x, um.y, um.z, um.w};
    float rj[4];
#pragma unroll
    for (int j = 0; j < 4; j++) {
        int t = t0 + j;
        int s = t & (Sn-1);
        float w = 0.f;
        if (nm_mask[c*Sn + s] == 0.f) w += cn * __expf(nts[t] - m1nc);
        if (umj[j] == 0.f)            w += cu * __expf(uts[t] - m1uc);
        rj[j] = w;
    }
    *(float4*)(W + (size_t)c * Tn + t0) = make_float4(rj[0], rj[1], rj[2], rj[3]);
}

// ---------------- K5: scatter mention weights via precomputed lists ----------------
__global__ __launch_bounds__(64) void k_scatter_men(
    const int* __restrict__ midx, const float* __restrict__ mwgt, const int* __restrict__ mcnt,
    const int* __restrict__ seg,
    const float* __restrict__ m_score, const float* __restrict__ denm,
    const float* __restrict__ segmax, const float* __restrict__ segden,
    const float* __restrict__ sc0, const float* __restrict__ sc1, const float* __restrict__ sc2,
    const float* __restrict__ denu, const float* __restrict__ b_comb_p,
    float* __restrict__ W)
{
    int m = blockIdx.x, tid = threadIdx.x;
    int c = seg[m];
    float a0, a1, a2;
    combine_attn(sc0[c], sc1[c], sc2[c], segden[c], denu[c], b_comb_p[0], a0, a1, a2);
    float coef = a1 * __expf(m_score[m] - segmax[c]) / segden[c] / denm[m];
    int n = mcnt[m];
    const int* gi = midx + (size_t)m * MCAP;
    const float* gwp = mwgt + (size_t)m * MCAP;
    float* Wc = W + (size_t)c * Tn;
    for (int i = tid; i < n; i += 64)
        atomicAdd(&Wc[gi[i]], coef * gwp[i]);
}

// ---------------- K6: partial GEMM — W staged in LDS (14 KB), SE direct from global ----------------
#define FMA4(A, WS, V) { A.x += (WS)*(V).x; A.y += (WS)*(V).y; A.z += (WS)*(V).z; A.w += (WS)*(V).w; }
__global__ __launch_bounds__(256) void k_out1(
    const float* __restrict__ W, const float* __restrict__ se, float* __restrict__ partial)
{
    int h0 = blockIdx.x * HT;    // h-fastest: 6 h-tiles of same p adjacent -> L2 row sharing
    int p  = blockIdx.y;         // 0..NP-1
    int tid = threadIdx.x;
    int x = tid & 31, y = tid >> 5;   // x: 32 h-quads, y: 8 c-groups of 7
    __shared__ float sW[56][64];      // 14 KB only -> 8 blocks/CU
    float4 acc[7];
#pragma unroll
    for (int i = 0; i < 7; i++) acc[i] = make_float4(0,0,0,0);
    for (int sub = 0; sub < 4; sub++) {
        int tbase = p*TC + sub*64;
        // stage W chunk: 56 x 64 = 896 float4
        for (int i = tid; i < 896; i += 256) {
            int c = i >> 4, f = i & 15;
            float4 v = (c < Cn) ? *(const float4*)(W + (size_t)c * Tn + tbase + f*4)
                                : make_float4(0,0,0,0);
            *(float4*)&sW[c][f*4] = v;
        }
        __syncthreads();
        for (int t4 = 0; t4 < 64; t4 += 4) {
            const float* sp = se + (size_t)(tbase + t4) * Hn + h0 + x*4;
            float4 v0 = *(const float4*)(sp);
            float4 v1 = *(const float4*)(sp + Hn);
            float4 v2 = *(const float4*)(sp + 2*Hn);
            float4 v3 = *(const float4*)(sp + 3*Hn);
#pragma unroll
            for (int cc = 0; cc < 7; cc++) {
                float4 wq = *(const float4*)&sW[y*7 + cc][t4];
                FMA4(acc[cc], wq.x, v0);
                FMA4(acc[cc], wq.y, v1);
                FMA4(acc[cc], wq.z, v2);
                FMA4(acc[cc], wq.w, v3);
            }
        }
        __syncthreads();
    }
#pragma unroll
    for (int cc = 0; cc < 7; cc++) {
        int c = y*7 + cc;
        if (c < Cn)
            *(float4*)(partial + ((size_t)p * Cn + c) * Hn + h0 + x*4) = acc[cc];
    }
}

// ---------------- K7: reduce partials over p (plain store) ----------------
__global__ __launch_bounds__(256) void k_out2(
    const float* __restrict__ partial, float* __restrict__ out)
{
    int cell = blockIdx.x * 256 + threadIdx.x;   // < Cn*Hn = 38400
    if (cell < Cn*Hn) {
        float s = 0.f;
#pragma unroll 8
        for (int p = 0; p < NP; p++)
            s += partial[(size_t)p * (Cn*Hn) + cell];
        out[cell] = s;
    }
}

extern "C" void kernel_launch(void* const* d_in, const int* in_sizes, int n_in,
                              void* d_out, int out_size, void* d_ws, size_t ws_size,
                              hipStream_t stream) {
    const float* se      = (const float*)d_in[0];
    const float* nm_mask = (const float*)d_in[1];
    const float* umask   = (const float*)d_in[2];
    const float* mmask   = (const float*)d_in[3];
    const int*   seg     = (const int*)  d_in[4];
    const float* w_ntok  = (const float*)d_in[5];
    const float* b_ntok  = (const float*)d_in[6];
    const float* w_name  = (const float*)d_in[7];
    const float* b_name  = (const float*)d_in[8];
    const float* w_mtok  = (const float*)d_in[9];
    const float* b_mtok  = (const float*)d_in[10];
    const float* w_men   = (const float*)d_in[11];
    const float* b_men   = (const float*)d_in[12];
    const float* w_utt   = (const float*)d_in[13];
    const float* b_utt   = (const float*)d_in[14];
    const float* w_comb  = (const float*)d_in[15];
    const float* b_comb  = (const float*)d_in[16];
    float* out = (float*)d_out;

    float* ws = (float*)d_ws;
    float* partial = ws;                               // NP*Cn*Hn = 4,915,200 f
    float* W       = partial + (size_t)NP*Cn*Hn;       // Cn*Tn = 1,638,400 f
    float* nts     = W + (size_t)Cn*Tn;                // Tn each:
    float* p_name  = nts + Tn;
    float* mts     = p_name + Tn;
    float* p_men   = mts + Tn;
    float* uts     = p_men + Tn;
    float* p_comb  = uts + Tn;
    float* n_score = p_comb + Tn;                      // Cn*Bn each:
    float* sc_n    = n_score + Cn*Bn;
    float* bw      = sc_n + Cn*Bn;
    float* m1n     = bw + Cn*Bn;
    float* denn    = m1n + Cn*Bn;
    float* m_score = denn + Cn*Bn;                     // Mn each:
    float* mcv     = m_score + Mn;
    float* denm    = mcv + Mn;
    float* mwgt    = denm + Mn;                        // Mn*MCAP floats
    int*   midx    = (int*)(mwgt + (size_t)Mn*MCAP);   // Mn*MCAP ints
    int*   mcnt    = midx + (size_t)Mn*MCAP;           // Mn ints
    float* segmax  = (float*)(mcnt + Mn);              // Cn each:
    float* segden  = segmax + Cn;
    float* sc0     = segden + Cn;
    float* sc1     = sc0 + Cn;
    float* sc2     = sc1 + Cn;
    float* m1u     = sc2 + Cn;
    float* denu    = m1u + Cn;

    k_proj<<<1024, 256, 0, stream>>>(se, w_ntok, b_ntok, w_name, w_mtok, b_mtok,
                                     w_men, w_utt, b_utt, w_comb,
                                     nts, p_name, mts, p_men, uts, p_comb);

    k_scan<<<Mn + Cn + (Cn*Bn)/4, 256, 0, stream>>>(
        mmask, mts, p_men, p_comb, b_men,
        umask, uts,
        nm_mask, nts, p_name, b_name,
        m_score, mcv, denm, midx, mwgt, mcnt,
        m1u, denu, sc2,
        n_score, sc_n, m1n, denn);

    k_small<<<2*Cn, 256, 0, stream>>>(n_score, sc_n, seg, m_score, mcv,
                                      bw, sc0, segmax, segden, sc1);

    k_buildW<<<dim3(Tn/1024, Cn), 256, 0, stream>>>(nm_mask, nts, m1n, denn, bw,
                                                    umask, uts, m1u, denu,
                                                    sc0, sc1, sc2, segden, b_comb, W);

    k_scatter_men<<<Mn, 64, 0, stream>>>(midx, mwgt, mcnt, seg, m_score, denm,
                                         segmax, segden, sc0, sc1, sc2, denu, b_comb, W);

    k_out1<<<dim3(Hn/HT, NP), 256, 0, stream>>>(W, se, partial);
    k_out2<<<(Cn*Hn + 255)/256, 256, 0, stream>>>(partial, out);
}

// Round 9
// 187.401 us; speedup vs baseline: 1.1694x; 1.1694x over previous
//
#include <hip/hip_runtime.h>
#include <cmath>

#define Bn 64
#define Sn 512
#define Hn 768
#define Cn 50
#define Mn 2000
#define Tn (Bn*Sn)   // 32768
#define MCAP 1024    // max active tokens per mention/utt row (E=328/655, +many sigma)
#define NP 128       // t-partitions for k_out
#define TC 256       // tokens per partition
#define HT 128       // h columns per tile

// ---------------- K1: per-token projections, weights in registers ----------------
__global__ __launch_bounds__(256) void k_proj(
    const float* __restrict__ se,
    const float* __restrict__ w_ntok, const float* __restrict__ b_ntok,
    const float* __restrict__ w_name,
    const float* __restrict__ w_mtok, const float* __restrict__ b_mtok,
    const float* __restrict__ w_men,
    const float* __restrict__ w_utt, const float* __restrict__ b_utt,
    const float* __restrict__ w_comb,
    float* __restrict__ nts, float* __restrict__ p_name,
    float* __restrict__ mts, float* __restrict__ p_men,
    float* __restrict__ uts, float* __restrict__ p_comb)
{
    int wv = threadIdx.x >> 6, lane = threadIdx.x & 63;
    int gw = blockIdx.x * 4 + wv;            // 0..4095, 8 rows each
    float4 w[6][3];
    const float4* warr[6] = {(const float4*)w_ntok, (const float4*)w_name,
                             (const float4*)w_mtok, (const float4*)w_men,
                             (const float4*)w_utt,  (const float4*)w_comb};
#pragma unroll
    for (int j = 0; j < 6; j++)
#pragma unroll
        for (int k = 0; k < 3; k++) w[j][k] = warr[j][lane + 64*k];
    float b0 = b_ntok[0], b2 = b_mtok[0], b4 = b_utt[0];
    for (int rr = 0; rr < 8; rr++) {
        int r = gw*8 + rr;
        const float4* se4 = (const float4*)(se + (size_t)r * Hn);
        float s0=0,s1=0,s2=0,s3=0,s4=0,s5=0;
#pragma unroll
        for (int k = 0; k < 3; k++) {
            float4 v = se4[lane + 64*k];
            s0 += v.x*w[0][k].x + v.y*w[0][k].y + v.z*w[0][k].z + v.w*w[0][k].w;
            s1 += v.x*w[1][k].x + v.y*w[1][k].y + v.z*w[1][k].z + v.w*w[1][k].w;
            s2 += v.x*w[2][k].x + v.y*w[2][k].y + v.z*w[2][k].z + v.w*w[2][k].w;
            s3 += v.x*w[3][k].x + v.y*w[3][k].y + v.z*w[3][k].z + v.w*w[3][k].w;
            s4 += v.x*w[4][k].x + v.y*w[4][k].y + v.z*w[4][k].z + v.w*w[4][k].w;
            s5 += v.x*w[5][k].x + v.y*w[5][k].y + v.z*w[5][k].z + v.w*w[5][k].w;
        }
#pragma unroll
        for (int off = 32; off >= 1; off >>= 1) {
            s0 += __shfl_xor(s0, off); s1 += __shfl_xor(s1, off);
            s2 += __shfl_xor(s2, off); s3 += __shfl_xor(s3, off);
            s4 += __shfl_xor(s4, off); s5 += __shfl_xor(s5, off);
        }
        if (lane == 0) {
            nts[r]    = s0 + b0;
            p_name[r] = s1;
            mts[r]    = s2 + b2;
            p_men[r]  = s3;
            uts[r]    = s4 + b4;
            p_comb[r] = s5;
        }
    }
}

// ---------------- K2: merged scan — mentions (0..1999) + utt (2000..2049) + names (2050..2849) ----
__global__ __launch_bounds__(256) void k_scan(
    const float* __restrict__ mmask, const float* __restrict__ mts,
    const float* __restrict__ p_men, const float* __restrict__ p_comb,
    const float* __restrict__ b_men_p,
    const float* __restrict__ umask, const float* __restrict__ uts,
    const float* __restrict__ nm_mask, const float* __restrict__ nts,
    const float* __restrict__ p_name, const float* __restrict__ b_name_p,
    float* __restrict__ m_score, float* __restrict__ mcv, float* __restrict__ denm,
    int* __restrict__ midx, float* __restrict__ mwgt, int* __restrict__ mcnt,
    float* __restrict__ m1u, float* __restrict__ denu, float* __restrict__ sc2,
    float* __restrict__ n_score, float* __restrict__ sc_n,
    float* __restrict__ m1n, float* __restrict__ denn)
{
    int tid = threadIdx.x;
    int wv = tid >> 6, lane = tid & 63;

    __shared__ int scnt;
    __shared__ int   sT[MCAP];
    __shared__ float sV[MCAP];
    __shared__ float sr1[4], sr2[4], sr3[4], sr4[4];

    if (blockIdx.x >= Mn + Cn) {
        // ---- names: one wave per (c,b) ----
        int idx = (blockIdx.x - Mn - Cn) * 4 + wv;   // c*Bn + b
        int c = idx >> 6, b = idx & 63;
        float v[8];
        float mx = -INFINITY;
#pragma unroll
        for (int k = 0; k < 8; k++) {
            int s = lane + 64*k;
            float val = nm_mask[c*Sn + s] + nts[b*Sn + s];   // -inf if masked
            v[k] = val;
            mx = fmaxf(mx, val);
        }
#pragma unroll
        for (int off = 32; off >= 1; off >>= 1) mx = fmaxf(mx, __shfl_xor(mx, off));
        float d = 0, sn = 0, sc = 0;
#pragma unroll
        for (int k = 0; k < 8; k++) {
            int s = lane + 64*k;
            int t = b*Sn + s;
            float e = __expf(v[k] - mx);
            d += e; sn += e * p_name[t]; sc += e * p_comb[t];
        }
#pragma unroll
        for (int off = 32; off >= 1; off >>= 1) {
            d += __shfl_xor(d, off); sn += __shfl_xor(sn, off); sc += __shfl_xor(sc, off);
        }
        if (lane == 0) {
            n_score[idx] = sn / d + b_name_p[0];
            sc_n[idx]    = sc / d;
            m1n[idx]     = mx;
            denn[idx]    = d;
        }
        return;
    }

    bool isU = blockIdx.x >= Mn;
    int row = isU ? (blockIdx.x - Mn) : blockIdx.x;
    if (tid == 0) scnt = 0;
    __syncthreads();

    const float4* row4 = (const float4*)((isU ? umask : mmask) + (size_t)row * Tn);
    const float*  vals = isU ? uts : mts;

    // phase 1: ballot compaction of indices only (mask stream is the sole load)
#pragma unroll 2
    for (int k = 0; k < Tn/4/256; k++) {
        int i = tid + k*256;
        float4 f = row4[i];
        float fm[4] = {f.x, f.y, f.z, f.w};
#pragma unroll
        for (int j = 0; j < 4; j++) {
            bool act = (fm[j] == 0.0f);
            unsigned long long bm = __ballot(act);
            if (bm) {
                int tot = __popcll(bm);
                int pos = __popcll(bm & ((1ull << lane) - 1ull));
                int base = 0;
                if (lane == 0) base = atomicAdd(&scnt, tot);
                base = __builtin_amdgcn_readfirstlane(base);
                int s = base + pos;
                if (act && s < MCAP) sT[s] = i*4 + j;
            }
        }
    }
    __syncthreads();
    int n = (scnt < MCAP) ? scnt : MCAP;

    // phase 2: gather values (L2-resident) + dense max
    float mx = -INFINITY;
    for (int i = tid; i < n; i += 256) {
        float v = vals[sT[i]];
        sV[i] = v;
        mx = fmaxf(mx, v);
    }
#pragma unroll
    for (int off = 32; off >= 1; off >>= 1) mx = fmaxf(mx, __shfl_xor(mx, off));
    if (lane == 0) sr1[wv] = mx;
    __syncthreads();
    mx = fmaxf(fmaxf(sr1[0], sr1[1]), fmaxf(sr1[2], sr1[3]));

    // phase 3: exp-sum + projection gathers (+ weight list for mentions)
    float d = 0, nm = 0, nc = 0;
    if (!isU) {
        int* gi = midx + (size_t)row * MCAP;
        float* gwp = mwgt + (size_t)row * MCAP;
        for (int i = tid; i < n; i += 256) {
            float e = __expf(sV[i] - mx);
            int t = sT[i];
            d += e; nm += e * p_men[t]; nc += e * p_comb[t];
            gi[i] = t; gwp[i] = e;
        }
    } else {
        for (int i = tid; i < n; i += 256) {
            float e = __expf(sV[i] - mx);
            d += e; nc += e * p_comb[sT[i]];
        }
    }
#pragma unroll
    for (int off = 32; off >= 1; off >>= 1) {
        d += __shfl_xor(d, off); nm += __shfl_xor(nm, off); nc += __shfl_xor(nc, off);
    }
    if (lane == 0) { sr2[wv] = d; sr3[wv] = nm; sr4[wv] = nc; }
    __syncthreads();
    if (tid == 0) {
        float dd = sr2[0]+sr2[1]+sr2[2]+sr2[3];
        float sm = sr3[0]+sr3[1]+sr3[2]+sr3[3];
        float sc = sr4[0]+sr4[1]+sr4[2]+sr4[3];
        if (!isU) {
            m_score[row] = sm/dd + b_men_p[0];
            mcv[row]     = sc/dd;
            denm[row]    = dd;
            mcnt[row]    = n;
        } else {
            m1u[row]  = mx;
            denu[row] = dd;
            sc2[row]  = (dd > 0.f) ? sc/dd : 0.f;
        }
    }
}

// ---------------- K3: small reductions — names-b softmax (0..49) + segment softmax (50..99) ----
__global__ __launch_bounds__(256) void k_small(
    const float* __restrict__ n_score, const float* __restrict__ sc_n,
    const int* __restrict__ seg, const float* __restrict__ m_score, const float* __restrict__ mcv,
    float* __restrict__ bw, float* __restrict__ sc0,
    float* __restrict__ segmax, float* __restrict__ segden, float* __restrict__ sc1)
{
    int tid = threadIdx.x;
    if (blockIdx.x < Cn) {
        int c = blockIdx.x;
        if (tid < 64) {
            int lane = tid;
            int idx = c*Bn + lane;
            float v = n_score[idx];
            float mx = v;
#pragma unroll
            for (int off = 32; off >= 1; off >>= 1) mx = fmaxf(mx, __shfl_xor(mx, off));
            float e = __expf(v - mx);
            float d = e, s = e * sc_n[idx];
#pragma unroll
            for (int off = 32; off >= 1; off >>= 1) { d += __shfl_xor(d, off); s += __shfl_xor(s, off); }
            bw[idx] = e / d;
            if (lane == 0) sc0[c] = s / d;
        }
    } else {
        int c = blockIdx.x - Cn;
        float mx = -INFINITY;
        for (int m = tid; m < Mn; m += 256)
            if (seg[m] == c) mx = fmaxf(mx, m_score[m]);
        __shared__ float sm[256];
        sm[tid] = mx; __syncthreads();
        for (int s = 128; s > 0; s >>= 1) { if (tid < s) sm[tid] = fmaxf(sm[tid], sm[tid+s]); __syncthreads(); }
        mx = sm[0];
        float d = 0, s1 = 0;
        if (mx != -INFINITY) {
            for (int m = tid; m < Mn; m += 256)
                if (seg[m] == c) { float e = __expf(m_score[m] - mx); d += e; s1 += e * mcv[m]; }
        }
        __shared__ float sd[256], ss[256];
        sd[tid] = d; ss[tid] = s1; __syncthreads();
        for (int s = 128; s > 0; s >>= 1) { if (tid < s) { sd[tid] += sd[tid+s]; ss[tid] += ss[tid+s]; } __syncthreads(); }
        if (tid == 0) {
            segmax[c] = mx;
            segden[c] = sd[0];
            sc1[c]    = (sd[0] > 0.f) ? ss[0]/sd[0] : 0.f;
        }
    }
}

// ---------------- combine-inline helper ----------------
__device__ inline void combine_attn(float sc0v, float sc1v, float sc2v,
                                    float sdn, float dnu, float bc,
                                    float& a0, float& a1, float& a2)
{
    float s0 = sc0v + bc;
    bool hasm = sdn > 0.f, hasu = dnu > 0.f;
    float s1 = hasm ? sc1v + bc : -INFINITY;
    float s2 = hasu ? sc2v + bc : -INFINITY;
    float mx = fmaxf(s0, fmaxf(s1, s2));
    float e0 = __expf(s0 - mx);
    float e1 = hasm ? __expf(s1 - mx) : 0.f;
    float e2 = hasu ? __expf(s2 - mx) : 0.f;
    float dd = e0 + e1 + e2;
    a0 = e0/dd; a1 = e1/dd; a2 = e2/dd;
}

// ---------------- K4: dense W init = name + utterance (no atomics) ----------------
__global__ __launch_bounds__(256) void k_buildW(
    const float* __restrict__ nm_mask, const float* __restrict__ nts,
    const float* __restrict__ m1n, const float* __restrict__ denn,
    const float* __restrict__ bw,
    const float* __restrict__ umask, const float* __restrict__ uts,
    const float* __restrict__ m1u, const float* __restrict__ denu,
    const float* __restrict__ sc0, const float* __restrict__ sc1, const float* __restrict__ sc2,
    const float* __restrict__ segden, const float* __restrict__ b_comb_p,
    float* __restrict__ W)
{
    int c = blockIdx.y;
    float a0, a1, a2;
    combine_attn(sc0[c], sc1[c], sc2[c], segden[c], denu[c], b_comb_p[0], a0, a1, a2);
    int t0 = (blockIdx.x * 256 + threadIdx.x) * 4;
    int b = t0 >> 9;
    float4 um = *(const float4*)(umask + (size_t)c * Tn + t0);
    float cn = a0 * bw[c*Bn + b] / denn[c*Bn + b];
    float m1nc = m1n[c*Bn + b];
    float du = denu[c];
    float cu = (du > 0.f) ? a2 / du : 0.f;
    float m1uc = m1u[c];
    float umj[4] = {um.x, um.y, um.z, um.w};
    float rj[4];
#pragma unroll
    for (int j = 0; j < 4; j++) {
        int t = t0 + j;
        int s = t & (Sn-1);
        float w = 0.f;
        if (nm_mask[c*Sn + s] == 0.f) w += cn * __expf(nts[t] - m1nc);
        if (umj[j] == 0.f)            w += cu * __expf(uts[t] - m1uc);
        rj[j] = w;
    }
    *(float4*)(W + (size_t)c * Tn + t0) = make_float4(rj[0], rj[1], rj[2], rj[3]);
}

// ---------------- K5: scatter mention weights via precomputed lists ----------------
__global__ __launch_bounds__(64) void k_scatter_men(
    const int* __restrict__ midx, const float* __restrict__ mwgt, const int* __restrict__ mcnt,
    const int* __restrict__ seg,
    const float* __restrict__ m_score, const float* __restrict__ denm,
    const float* __restrict__ segmax, const float* __restrict__ segden,
    const float* __restrict__ sc0, const float* __restrict__ sc1, const float* __restrict__ sc2,
    const float* __restrict__ denu, const float* __restrict__ b_comb_p,
    float* __restrict__ W)
{
    int m = blockIdx.x, tid = threadIdx.x;
    int c = seg[m];
    float a0, a1, a2;
    combine_attn(sc0[c], sc1[c], sc2[c], segden[c], denu[c], b_comb_p[0], a0, a1, a2);
    float coef = a1 * __expf(m_score[m] - segmax[c]) / segden[c] / denm[m];
    int n = mcnt[m];
    const int* gi = midx + (size_t)m * MCAP;
    const float* gwp = mwgt + (size_t)m * MCAP;
    float* Wc = W + (size_t)c * Tn;
    for (int i = tid; i < n; i += 64)
        atomicAdd(&Wc[gi[i]], coef * gwp[i]);
}

// ---------------- K6: partial GEMM, SE staged through LDS, vectorized sW reads ----------------
#define FMA4(A, WS, V) { A.x += (WS)*(V).x; A.y += (WS)*(V).y; A.z += (WS)*(V).z; A.w += (WS)*(V).w; }
__global__ __launch_bounds__(256) void k_out1(
    const float* __restrict__ W, const float* __restrict__ se, float* __restrict__ partial)
{
    int p = blockIdx.x;
    int h0 = blockIdx.y * HT;
    int tid = threadIdx.x;
    int x = tid & 31, y = tid >> 5;
    __shared__ float sW[56][64];
    __shared__ float sS[64][128];
    float4 acc[7];
#pragma unroll
    for (int i = 0; i < 7; i++) acc[i] = make_float4(0,0,0,0);
    for (int sub = 0; sub < 4; sub++) {
        int tbase = p*TC + sub*64;
        for (int i = tid; i < 896; i += 256) {
            int c = i >> 4, f = i & 15;
            float4 v = (c < Cn) ? *(const float4*)(W + (size_t)c * Tn + tbase + f*4)
                                : make_float4(0,0,0,0);
            *(float4*)&sW[c][f*4] = v;
        }
#pragma unroll
        for (int q = 0; q < 8; q++) {
            int idx = tid + q*256;
            int row = idx >> 5, col = idx & 31;
            *(float4*)&sS[row][col*4] =
                *(const float4*)(se + (size_t)(tbase + row) * Hn + h0 + col*4);
        }
        __syncthreads();
        for (int t4 = 0; t4 < 64; t4 += 4) {
            float4 wq[7];
#pragma unroll
            for (int cc = 0; cc < 7; cc++)
                wq[cc] = *(const float4*)&sW[y*7 + cc][t4];
            float4 v0 = *(const float4*)&sS[t4+0][x*4];
            float4 v1 = *(const float4*)&sS[t4+1][x*4];
            float4 v2 = *(const float4*)&sS[t4+2][x*4];
            float4 v3 = *(const float4*)&sS[t4+3][x*4];
#pragma unroll
            for (int cc = 0; cc < 7; cc++) {
                FMA4(acc[cc], wq[cc].x, v0);
                FMA4(acc[cc], wq[cc].y, v1);
                FMA4(acc[cc], wq[cc].z, v2);
                FMA4(acc[cc], wq[cc].w, v3);
            }
        }
        __syncthreads();
    }
#pragma unroll
    for (int cc = 0; cc < 7; cc++) {
        int c = y*7 + cc;
        if (c < Cn)
            *(float4*)(partial + ((size_t)p * Cn + c) * Hn + h0 + x*4) = acc[cc];
    }
}

// ---------------- K7: reduce partials over p (plain store) ----------------
__global__ __launch_bounds__(256) void k_out2(
    const float* __restrict__ partial, float* __restrict__ out)
{
    int cell = blockIdx.x * 256 + threadIdx.x;
    if (cell < Cn*Hn) {
        float s = 0.f;
#pragma unroll 8
        for (int p = 0; p < NP; p++)
            s += partial[(size_t)p * (Cn*Hn) + cell];
        out[cell] = s;
    }
}

extern "C" void kernel_launch(void* const* d_in, const int* in_sizes, int n_in,
                              void* d_out, int out_size, void* d_ws, size_t ws_size,
                              hipStream_t stream) {
    const float* se      = (const float*)d_in[0];
    const float* nm_mask = (const float*)d_in[1];
    const float* umask   = (const float*)d_in[2];
    const float* mmask   = (const float*)d_in[3];
    const int*   seg     = (const int*)  d_in[4];
    const float* w_ntok  = (const float*)d_in[5];
    const float* b_ntok  = (const float*)d_in[6];
    const float* w_name  = (const float*)d_in[7];
    const float* b_name  = (const float*)d_in[8];
    const float* w_mtok  = (const float*)d_in[9];
    const float* b_mtok  = (const float*)d_in[10];
    const float* w_men   = (const float*)d_in[11];
    const float* b_men   = (const float*)d_in[12];
    const float* w_utt   = (const float*)d_in[13];
    const float* b_utt   = (const float*)d_in[14];
    const float* w_comb  = (const float*)d_in[15];
    const float* b_comb  = (const float*)d_in[16];
    float* out = (float*)d_out;

    float* ws = (float*)d_ws;
    float* partial = ws;                               // NP*Cn*Hn = 4,915,200 f
    float* W       = partial + (size_t)NP*Cn*Hn;       // Cn*Tn = 1,638,400 f
    float* nts     = W + (size_t)Cn*Tn;                // Tn each:
    float* p_name  = nts + Tn;
    float* mts     = p_name + Tn;
    float* p_men   = mts + Tn;
    float* uts     = p_men + Tn;
    float* p_comb  = uts + Tn;
    float* n_score = p_comb + Tn;                      // Cn*Bn each:
    float* sc_n    = n_score + Cn*Bn;
    float* bw      = sc_n + Cn*Bn;
    float* m1n     = bw + Cn*Bn;
    float* denn    = m1n + Cn*Bn;
    float* m_score = denn + Cn*Bn;                     // Mn each:
    float* mcv     = m_score + Mn;
    float* denm    = mcv + Mn;
    float* mwgt    = denm + Mn;                        // Mn*MCAP floats
    int*   midx    = (int*)(mwgt + (size_t)Mn*MCAP);   // Mn*MCAP ints
    int*   mcnt    = midx + (size_t)Mn*MCAP;           // Mn ints
    float* segmax  = (float*)(mcnt + Mn);              // Cn each:
    float* segden  = segmax + Cn;
    float* sc0     = segden + Cn;
    float* sc1     = sc0 + Cn;
    float* sc2     = sc1 + Cn;
    float* m1u     = sc2 + Cn;
    float* denu    = m1u + Cn;

    k_proj<<<1024, 256, 0, stream>>>(se, w_ntok, b_ntok, w_name, w_mtok, b_mtok,
                                     w_men, w_utt, b_utt, w_comb,
                                     nts, p_name, mts, p_men, uts, p_comb);

    k_scan<<<Mn + Cn + (Cn*Bn)/4, 256, 0, stream>>>(
        mmask, mts, p_men, p_comb, b_men,
        umask, uts,
        nm_mask, nts, p_name, b_name,
        m_score, mcv, denm, midx, mwgt, mcnt,
        m1u, denu, sc2,
        n_score, sc_n, m1n, denn);

    k_small<<<2*Cn, 256, 0, stream>>>(n_score, sc_n, seg, m_score, mcv,
                                      bw, sc0, segmax, segden, sc1);

    k_buildW<<<dim3(Tn/1024, Cn), 256, 0, stream>>>(nm_mask, nts, m1n, denn, bw,
                                                    umask, uts, m1u, denu,
                                                    sc0, sc1, sc2, segden, b_comb, W);

    k_scatter_men<<<Mn, 64, 0, stream>>>(midx, mwgt, mcnt, seg, m_score, denm,
                                         segmax, segden, sc0, sc1, sc2, denu, b_comb, W);

    k_out1<<<dim3(NP, Hn/HT), 256, 0, stream>>>(W, se, partial);
    k_out2<<<(Cn*Hn + 255)/256, 256, 0, stream>>>(partial, out);
}